// Round 6
// baseline (281.002 us; speedup 1.0000x reference)
//
#include <hip/hip_runtime.h>
#include <stdint.h>

#define DIM 1024
#define SEQ 2048
#define BATCH 4
#define ROWS (BATCH*SEQ)          /* 8192 */
// attention scale folded into Q: 0.125 * log2(e)
#define QSCALE 0.1803368801111f

typedef __attribute__((ext_vector_type(8))) short bf16x8;   // 8 bf16 in 4 VGPRs
typedef __attribute__((ext_vector_type(4))) float f32x4;
typedef __attribute__((ext_vector_type(4))) _Float16 f16x4;
typedef __attribute__((ext_vector_type(2))) __fp16 fp16x2_raw;  // cvt_pkrtz return type

#if __has_builtin(__builtin_amdgcn_exp2f)
#define EXP2F(x) __builtin_amdgcn_exp2f(x)
#else
#define EXP2F(x) __expf((x) * 0.69314718056f)
#endif

#define MFMA16x16(a,b,c) __builtin_amdgcn_mfma_f32_16x16x16f16(a,b,c,0,0,0)

// ---- fp32 -> bf16 RNE ----
__device__ __forceinline__ unsigned short f2bf(float f) {
  union { float f; unsigned int u; } v; v.f = f;
  unsigned int u = v.u;
  return (unsigned short)((u + 0x7FFFu + ((u >> 16) & 1u)) >> 16);
}

// ---- fp32 -> fp16 RNE (bits) ----
__device__ __forceinline__ unsigned short f2h(float f) {
  union { _Float16 h; unsigned short u; } v;
  v.h = (_Float16)f;
  return v.u;
}

// pack two f32 -> fp16x2 dword (v_cvt_pkrtz_f16_f32), returned as raw bits
__device__ __forceinline__ unsigned int pkrtz_bits(float lo, float hi) {
  union { fp16x2_raw h; unsigned int u; } v;
  v.h = __builtin_amdgcn_cvt_pkrtz(lo, hi);
  return v.u;
}

// ---- async global->LDS, 16B per lane (wave-uniform LDS base + lane*16) ----
__device__ __forceinline__ void gload_lds16(const void* g, void* l) {
  __builtin_amdgcn_global_load_lds(
      (const __attribute__((address_space(1))) unsigned int*)g,
      (__attribute__((address_space(3))) unsigned int*)l,
      16, 0, 0);
}

// ---- fused cast kernel: x (8M) | w_qkv (3M) | w_proj (1M) fp32 -> bf16 ----
__global__ void cast_all(const float* __restrict__ x,
                         const float* __restrict__ wq,
                         const float* __restrict__ wp,
                         unsigned short* __restrict__ xb,
                         unsigned short* __restrict__ wqb,
                         unsigned short* __restrict__ wpb) {
  const int i = (blockIdx.x * blockDim.x + threadIdx.x) * 4;
  const float* src;
  unsigned short* dst;
  int off;
  if (i < ROWS * DIM)                 { src = x;  dst = xb;  off = i; }
  else if (i < ROWS * DIM + 3 * DIM * DIM) { src = wq; dst = wqb; off = i - ROWS * DIM; }
  else                                { src = wp; dst = wpb; off = i - ROWS * DIM - 3 * DIM * DIM; }
  float4 f = *(const float4*)(src + off);
  ushort4 o;
  o.x = f2bf(f.x); o.y = f2bf(f.y); o.z = f2bf(f.z); o.w = f2bf(f.w);
  *(ushort4*)(dst + off) = o;
}

// ---- QKV GEMM: C[8192,3072] = X @ Wqkv^T; scatter Q(*qscale),K bf16; V^T fp16.
__global__ __launch_bounds__(256) void gemm_qkv(
    const unsigned short* __restrict__ A,
    const unsigned short* __restrict__ W,
    unsigned short* __restrict__ qb,
    unsigned short* __restrict__ kb,
    unsigned short* __restrict__ vtb) {
  const int K = DIM;
  __shared__ unsigned short Al[128 * 32];
  __shared__ unsigned short Wl[128 * 32];
  const int tid  = threadIdx.x;
  const int wave = tid >> 6, lane = tid & 63;
  const int quad = lane >> 4, l16 = lane & 15;
  const int m0 = blockIdx.y * 128, n0 = blockIdx.x * 128;
  const int wr = (wave >> 1) * 64, wc = (wave & 1) * 64;
  const int which = n0 >> 10;  // 0=Q, 1=K, 2=V (uniform per block)

  f32x4 acc[4][4];
#pragma unroll
  for (int i = 0; i < 4; i++)
#pragma unroll
    for (int j = 0; j < 4; j++) acc[i][j] = (f32x4)0.f;

  const int arow = wave * 16 + (lane >> 2);
  const int acol = (lane & 3) * 8;
  const unsigned short* Ag = A + (size_t)(m0 + arow) * K + acol;
  const unsigned short* Wg = W + (size_t)(n0 + arow) * K + acol;

  if (which < 2) {
    for (int kt = 0; kt < K; kt += 32) {
      __syncthreads();
#pragma unroll
      for (int i = 0; i < 2; i++) {
        gload_lds16((const void*)(Ag + (size_t)(i * 64) * K + kt), (void*)&Al[i * 2048 + wave * 512]);
        gload_lds16((const void*)(Wg + (size_t)(i * 64) * K + kt), (void*)&Wl[i * 2048 + wave * 512]);
      }
      __syncthreads();
      bf16x8 af[4], wf[4];
#pragma unroll
      for (int i = 0; i < 4; i++) {
        af[i] = *(const bf16x8*)&Al[(wr + i * 16 + l16) * 32 + quad * 8];
        wf[i] = *(const bf16x8*)&Wl[(wc + i * 16 + l16) * 32 + quad * 8];
      }
#pragma unroll
      for (int i = 0; i < 4; i++)
#pragma unroll
        for (int j = 0; j < 4; j++)
          acc[i][j] = __builtin_amdgcn_mfma_f32_16x16x32_bf16(wf[j], af[i], acc[i][j], 0, 0, 0);
    }
    // epilogue (transposed frag): row=quad*4+r -> feature, col=l16 -> token
    const float sc = (which == 0) ? QSCALE : 1.f;
    unsigned short* base = (which == 0) ? qb : kb;
#pragma unroll
    for (int i = 0; i < 4; i++) {
      const int tok = m0 + wr + i * 16 + l16;
      const int b = tok >> 11, n = tok & 2047;
#pragma unroll
      for (int j = 0; j < 4; j++) {
        const int col0 = n0 + wc + j * 16 + quad * 4;
        const int h = (col0 >> 6) & 15, d = col0 & 63;
        ushort4 o4;
        o4.x = f2bf(acc[i][j][0] * sc); o4.y = f2bf(acc[i][j][1] * sc);
        o4.z = f2bf(acc[i][j][2] * sc); o4.w = f2bf(acc[i][j][3] * sc);
        *(ushort4*)&base[((size_t)(b * 16 + h) * SEQ + n) * 64 + d] = o4;
      }
    }
  } else {
    for (int kt = 0; kt < K; kt += 32) {
      __syncthreads();
#pragma unroll
      for (int i = 0; i < 2; i++) {
        gload_lds16((const void*)(Ag + (size_t)(i * 64) * K + kt), (void*)&Al[i * 2048 + wave * 512]);
        gload_lds16((const void*)(Wg + (size_t)(i * 64) * K + kt), (void*)&Wl[i * 2048 + wave * 512]);
      }
      __syncthreads();
      bf16x8 af[4], wf[4];
#pragma unroll
      for (int i = 0; i < 4; i++) {
        af[i] = *(const bf16x8*)&Al[(wr + i * 16 + l16) * 32 + quad * 8];
        wf[i] = *(const bf16x8*)&Wl[(wc + i * 16 + l16) * 32 + quad * 8];
      }
#pragma unroll
      for (int i = 0; i < 4; i++)
#pragma unroll
        for (int j = 0; j < 4; j++)
          acc[i][j] = __builtin_amdgcn_mfma_f32_16x16x32_bf16(af[i], wf[j], acc[i][j], 0, 0, 0);
    }
    // epilogue (normal frag): 4 consecutive tokens per lane -> V^T fp16 ushort4
#pragma unroll
    for (int i = 0; i < 4; i++) {
      const int row = m0 + wr + i * 16 + quad * 4;
      const int b = row >> 11, n = row & 2047;
#pragma unroll
      for (int j = 0; j < 4; j++) {
        const int col = n0 + wc + j * 16 + l16;
        const int h = (col >> 6) & 15, d = col & 63;
        ushort4 o4;
        o4.x = f2h(acc[i][j][0]); o4.y = f2h(acc[i][j][1]);
        o4.z = f2h(acc[i][j][2]); o4.w = f2h(acc[i][j][3]);
        *(ushort4*)&vtb[((size_t)(b * 16 + h) * 64 + d) * SEQ + n] = o4;
      }
    }
  }
}

// ---- flash attention: S^T = K*Q^T (bf16 16x16x32), exp2 -> fp16 P in-register,
// PV + ones-denominator via 16x16x16 f16 MFMA (P's A-frag == S^T C-frag layout).
// No P LDS roundtrip. Double-buffered K/V, one barrier per 64-key tile.
__global__ __launch_bounds__(256, 2) void attn_kernel(
    const unsigned short* __restrict__ qb,   // [bh][n][d] bf16, pre-scaled by QSCALE
    const unsigned short* __restrict__ kb,   // [bh][n][d] bf16
    const unsigned short* __restrict__ vtb,  // [bh][d][n] fp16
    unsigned short* __restrict__ out) {      // [8192][1024] bf16
  __shared__ unsigned short Kl[2][64 * 64];  // [key][d], 16B chunk c at c^(row&7)
  __shared__ unsigned short Vl[2][64 * 64];  // [d][key] fp16 bits, same swizzle

  const int tid  = threadIdx.x;
  const int wave = tid >> 6, lane = tid & 63;
  const int quad = lane >> 4, l16 = lane & 15;
  const int qtile = blockIdx.x;           // 0..7
  const int bh    = blockIdx.y;           // 0..63
  const size_t qkbase = (size_t)bh * SEQ * 64;
  const int q0 = qtile * 256 + wave * 64;

  // Q B-frags: Q[n=l16][k=kk*32+quad*8+j]
  bf16x8 qf[4][2];
#pragma unroll
  for (int mi = 0; mi < 4; mi++)
#pragma unroll
    for (int kk = 0; kk < 2; kk++)
      qf[mi][kk] = *(const bf16x8*)&qb[qkbase + (size_t)(q0 + mi * 16 + l16) * 64 + kk * 32 + quad * 8];

  f32x4 o[4][4];
#pragma unroll
  for (int mi = 0; mi < 4; mi++)
#pragma unroll
    for (int nt = 0; nt < 4; nt++) o[mi][nt] = (f32x4)0.f;
  f32x4 lacc[4];
#pragma unroll
  for (int mi = 0; mi < 4; mi++) lacc[mi] = (f32x4)0.f;

  union { f16x4 v; unsigned int d[2]; } ones;
  ones.d[0] = 0x3C003C00u; ones.d[1] = 0x3C003C00u;  // fp16 1.0 x4

  const unsigned short* Kg = kb + qkbase;
  const unsigned short* Vg = vtb + (size_t)bh * 64 * SEQ;
  const int srow = tid >> 3;   // 0..31
  const int schk = tid & 7;

  auto stage = [&](int kt, int buf) {
#pragma unroll
    for (int p = 0; p < 2; p++) {
      const int r = p * 32 + srow;
      const int sw = schk ^ (r & 7);
      gload_lds16((const void*)(Kg + (size_t)(kt + r) * 64 + sw * 8),
                  (void*)&Kl[buf][p * 2048 + wave * 512]);
      gload_lds16((const void*)(Vg + (size_t)r * SEQ + kt + sw * 8),
                  (void*)&Vl[buf][p * 2048 + wave * 512]);
    }
  };

  stage(0, 0);

  int buf = 0;
  for (int kt = 0; kt < SEQ; kt += 64, buf ^= 1) {
    __syncthreads();  // tile `buf` staged; prev reads of buf^1 done
    if (kt + 64 < SEQ) stage(kt + 64, buf ^ 1);

#pragma unroll
    for (int nh = 0; nh < 4; nh++) {
      // K A-frags: A[m=key=l16 (+16*nh)][k=d=quad*8+j]
      const int R = nh * 16 + l16;
      const int sb = R & 7;
      bf16x8 kf0 = *(const bf16x8*)&Kl[buf][R * 64 + ((quad ^ sb) << 3)];
      bf16x8 kf1 = *(const bf16x8*)&Kl[buf][R * 64 + (((4 + quad) ^ sb) << 3)];
      // V B-frags (16x16x16): B[n=d=nt*16+l16][k=key=quad*4+j (+16*nh)], b64 reads
      f16x4 vf[4];
#pragma unroll
      for (int nt = 0; nt < 4; nt++) {
        const int vr = nt * 16 + l16;
        const int c = nh * 2 + (quad >> 1);
        vf[nt] = *(const f16x4*)&Vl[buf][vr * 64 + (((c ^ (vr & 7)) << 3) | ((quad & 1) << 2))];
      }
#pragma unroll
      for (int mi = 0; mi < 4; mi++) {
        // S^T: C[row=key=quad*4+r][col=q=l16]
        f32x4 s = (f32x4)0.f;
        s = __builtin_amdgcn_mfma_f32_16x16x32_bf16(kf0, qf[mi][0], s, 0, 0, 0);
        s = __builtin_amdgcn_mfma_f32_16x16x32_bf16(kf1, qf[mi][1], s, 0, 0, 0);
        // P = exp2(S^T) packed fp16 -> A-frag of 16x16x16: A[m=q=l16][k=key=quad*4+j]
        union { f16x4 v; unsigned int d[2]; } pu;
        pu.d[0] = pkrtz_bits(EXP2F(s[0]), EXP2F(s[1]));
        pu.d[1] = pkrtz_bits(EXP2F(s[2]), EXP2F(s[3]));
        lacc[mi] = MFMA16x16(pu.v, ones.v, lacc[mi]);
#pragma unroll
        for (int nt = 0; nt < 4; nt++)
          o[mi][nt] = MFMA16x16(pu.v, vf[nt], o[mi][nt]);
      }
    }
  }

  const int h = bh & 15, b = bh >> 4;
#pragma unroll
  for (int mi = 0; mi < 4; mi++) {
    float inv[4];
#pragma unroll
    for (int r = 0; r < 4; r++) inv[r] = 1.f / lacc[mi][r];
#pragma unroll
    for (int nt = 0; nt < 4; nt++)
#pragma unroll
      for (int r = 0; r < 4; r++)
        out[((size_t)(b * SEQ + q0 + mi * 16 + quad * 4 + r)) * DIM + h * 64 + nt * 16 + l16] =
            f2bf(o[mi][nt][r] * inv[r]);
  }
}

// ---- proj GEMM: out[8192,1024] fp32 = Ao bf16 @ Wproj^T + bias ----
__global__ __launch_bounds__(256) void gemm_proj(
    const unsigned short* __restrict__ A,
    const unsigned short* __restrict__ W,
    float* __restrict__ out,
    const float* __restrict__ bias) {
  const int N = DIM, K = DIM;
  __shared__ unsigned short Al[128 * 32];
  __shared__ unsigned short Wl[128 * 32];
  const int tid  = threadIdx.x;
  const int wave = tid >> 6, lane = tid & 63;
  const int quad = lane >> 4, l16 = lane & 15;
  const int m0 = blockIdx.y * 128, n0 = blockIdx.x * 128;
  const int wr = (wave >> 1) * 64, wc = (wave & 1) * 64;

  f32x4 acc[4][4];
#pragma unroll
  for (int i = 0; i < 4; i++)
#pragma unroll
    for (int j = 0; j < 4; j++) acc[i][j] = (f32x4)0.f;

  const int arow = wave * 16 + (lane >> 2);
  const int acol = (lane & 3) * 8;
  const unsigned short* Ag = A + (size_t)(m0 + arow) * K + acol;
  const unsigned short* Wg = W + (size_t)(n0 + arow) * K + acol;

  for (int kt = 0; kt < K; kt += 32) {
    __syncthreads();
#pragma unroll
    for (int i = 0; i < 2; i++) {
      gload_lds16((const void*)(Ag + (size_t)(i * 64) * K + kt), (void*)&Al[i * 2048 + wave * 512]);
      gload_lds16((const void*)(Wg + (size_t)(i * 64) * K + kt), (void*)&Wl[i * 2048 + wave * 512]);
    }
    __syncthreads();

    bf16x8 af[4], wf[4];
#pragma unroll
    for (int i = 0; i < 4; i++) {
      af[i] = *(const bf16x8*)&Al[(wr + i * 16 + l16) * 32 + quad * 8];
      wf[i] = *(const bf16x8*)&Wl[(wc + i * 16 + l16) * 32 + quad * 8];
    }
#pragma unroll
    for (int i = 0; i < 4; i++)
#pragma unroll
      for (int j = 0; j < 4; j++)
        acc[i][j] = __builtin_amdgcn_mfma_f32_16x16x32_bf16(af[i], wf[j], acc[i][j], 0, 0, 0);
  }

#pragma unroll
  for (int i = 0; i < 4; i++) {
    const int row = m0 + wr + i * 16 + quad * 4;
#pragma unroll
    for (int j = 0; j < 4; j++) {
      const int col = n0 + wc + j * 16 + l16;
      const float bv = bias[col];
#pragma unroll
      for (int r = 0; r < 4; r++)
        out[(size_t)(row + r) * N + col] = acc[i][j][r] + bv;
    }
  }
}

extern "C" void kernel_launch(void* const* d_in, const int* in_sizes, int n_in,
                              void* d_out, int out_size, void* d_ws, size_t ws_size,
                              hipStream_t stream) {
  const float* x      = (const float*)d_in[0];
  const float* w_qkv  = (const float*)d_in[1];
  const float* w_proj = (const float*)d_in[2];
  const float* b_proj = (const float*)d_in[3];
  float* outp = (float*)d_out;

  char* ws = (char*)d_ws;
  unsigned short* xb     = (unsigned short*)(ws);                        // 16 MB
  unsigned short* wqkvb  = (unsigned short*)(ws + (16u << 20));          // 6 MB
  unsigned short* wprojb = (unsigned short*)(ws + (22u << 20));          // 2 MB
  unsigned short* qb     = (unsigned short*)(ws + (24u << 20));          // 16 MB
  unsigned short* kb     = (unsigned short*)(ws + (40u << 20));          // 16 MB
  unsigned short* vtb    = (unsigned short*)(ws + (56u << 20));          // 16 MB (fp16)
  unsigned short* aout   = (unsigned short*)(ws + (72u << 20));          // 16 MB

  const int total4 = (ROWS * DIM + 3 * DIM * DIM + DIM * DIM) / 4;  // 3,145,728
  cast_all<<<total4 / 256, 256, 0, stream>>>(x, w_qkv, w_proj, xb, wqkvb, wprojb);

  gemm_qkv<<<dim3(24, 64), 256, 0, stream>>>(xb, wqkvb, qb, kb, vtb);
  attn_kernel<<<dim3(8, 64), 256, 0, stream>>>(qb, kb, vtb, aout);
  gemm_proj<<<dim3(8, 64), 256, 0, stream>>>(aout, wprojb, outp, b_proj);
}

// Round 7
// 254.780 us; speedup vs baseline: 1.1029x; 1.1029x over previous
//
#include <hip/hip_runtime.h>
#include <stdint.h>

#define DIM 1024
#define SEQ 2048
#define BATCH 4
#define ROWS (BATCH*SEQ)          /* 8192 */
// attention scale folded into Q: 0.125 * log2(e)
#define QSCALE 0.1803368801111f

typedef __attribute__((ext_vector_type(8))) short bf16x8;   // 8 bf16 in 4 VGPRs
typedef __attribute__((ext_vector_type(4))) float f32x4;
typedef __attribute__((ext_vector_type(8))) _Float16 f16x8;
typedef __attribute__((ext_vector_type(2))) __fp16 fp16x2_raw;  // cvt_pkrtz return type

#if __has_builtin(__builtin_amdgcn_exp2f)
#define EXP2F(x) __builtin_amdgcn_exp2f(x)
#else
#define EXP2F(x) __expf((x) * 0.69314718056f)
#endif

#define MFMA_BF16_K32(a,b,c) __builtin_amdgcn_mfma_f32_16x16x32_bf16(a,b,c,0,0,0)
#define MFMA_F16_K32(a,b,c)  __builtin_amdgcn_mfma_f32_16x16x32_f16(a,b,c,0,0,0)

// ---- fp32 -> bf16 RNE ----
__device__ __forceinline__ unsigned short f2bf(float f) {
  union { float f; unsigned int u; } v; v.f = f;
  unsigned int u = v.u;
  return (unsigned short)((u + 0x7FFFu + ((u >> 16) & 1u)) >> 16);
}

// ---- fp32 -> fp16 RNE (bits) ----
__device__ __forceinline__ unsigned short f2h(float f) {
  union { _Float16 h; unsigned short u; } v;
  v.h = (_Float16)f;
  return v.u;
}

// pack two f32 -> fp16x2 dword (v_cvt_pkrtz_f16_f32), returned as raw bits
__device__ __forceinline__ unsigned int pkrtz_bits(float lo, float hi) {
  union { fp16x2_raw h; unsigned int u; } v;
  v.h = __builtin_amdgcn_cvt_pkrtz(lo, hi);
  return v.u;
}

// ---- async global->LDS, 16B per lane (wave-uniform LDS base + lane*16) ----
__device__ __forceinline__ void gload_lds16(const void* g, void* l) {
  __builtin_amdgcn_global_load_lds(
      (const __attribute__((address_space(1))) unsigned int*)g,
      (__attribute__((address_space(3))) unsigned int*)l,
      16, 0, 0);
}

// ---- fused cast kernel: x (8M) | w_qkv (3M) | w_proj (1M) fp32 -> bf16 ----
__global__ void cast_all(const float* __restrict__ x,
                         const float* __restrict__ wq,
                         const float* __restrict__ wp,
                         unsigned short* __restrict__ xb,
                         unsigned short* __restrict__ wqb,
                         unsigned short* __restrict__ wpb) {
  const int i = (blockIdx.x * blockDim.x + threadIdx.x) * 4;
  const float* src;
  unsigned short* dst;
  int off;
  if (i < ROWS * DIM)                 { src = x;  dst = xb;  off = i; }
  else if (i < ROWS * DIM + 3 * DIM * DIM) { src = wq; dst = wqb; off = i - ROWS * DIM; }
  else                                { src = wp; dst = wpb; off = i - ROWS * DIM - 3 * DIM * DIM; }
  float4 f = *(const float4*)(src + off);
  ushort4 o;
  o.x = f2bf(f.x); o.y = f2bf(f.y); o.z = f2bf(f.z); o.w = f2bf(f.w);
  *(ushort4*)(dst + off) = o;
}

// ---- QKV GEMM: C[8192,3072] = X @ Wqkv^T; scatter Q(*qscale),K bf16; V^T fp16.
__global__ __launch_bounds__(256) void gemm_qkv(
    const unsigned short* __restrict__ A,
    const unsigned short* __restrict__ W,
    unsigned short* __restrict__ qb,
    unsigned short* __restrict__ kb,
    unsigned short* __restrict__ vtb) {
  const int K = DIM;
  __shared__ unsigned short Al[128 * 32];
  __shared__ unsigned short Wl[128 * 32];
  const int tid  = threadIdx.x;
  const int wave = tid >> 6, lane = tid & 63;
  const int quad = lane >> 4, l16 = lane & 15;
  const int m0 = blockIdx.y * 128, n0 = blockIdx.x * 128;
  const int wr = (wave >> 1) * 64, wc = (wave & 1) * 64;
  const int which = n0 >> 10;  // 0=Q, 1=K, 2=V (uniform per block)

  f32x4 acc[4][4];
#pragma unroll
  for (int i = 0; i < 4; i++)
#pragma unroll
    for (int j = 0; j < 4; j++) acc[i][j] = (f32x4)0.f;

  const int arow = wave * 16 + (lane >> 2);
  const int acol = (lane & 3) * 8;
  const unsigned short* Ag = A + (size_t)(m0 + arow) * K + acol;
  const unsigned short* Wg = W + (size_t)(n0 + arow) * K + acol;

  if (which < 2) {
    for (int kt = 0; kt < K; kt += 32) {
      __syncthreads();
#pragma unroll
      for (int i = 0; i < 2; i++) {
        gload_lds16((const void*)(Ag + (size_t)(i * 64) * K + kt), (void*)&Al[i * 2048 + wave * 512]);
        gload_lds16((const void*)(Wg + (size_t)(i * 64) * K + kt), (void*)&Wl[i * 2048 + wave * 512]);
      }
      __syncthreads();
      bf16x8 af[4], wf[4];
#pragma unroll
      for (int i = 0; i < 4; i++) {
        af[i] = *(const bf16x8*)&Al[(wr + i * 16 + l16) * 32 + quad * 8];
        wf[i] = *(const bf16x8*)&Wl[(wc + i * 16 + l16) * 32 + quad * 8];
      }
#pragma unroll
      for (int i = 0; i < 4; i++)
#pragma unroll
        for (int j = 0; j < 4; j++)
          acc[i][j] = __builtin_amdgcn_mfma_f32_16x16x32_bf16(wf[j], af[i], acc[i][j], 0, 0, 0);
    }
    // epilogue (transposed frag): row=quad*4+r -> feature, col=l16 -> token
    const float sc = (which == 0) ? QSCALE : 1.f;
    unsigned short* base = (which == 0) ? qb : kb;
#pragma unroll
    for (int i = 0; i < 4; i++) {
      const int tok = m0 + wr + i * 16 + l16;
      const int b = tok >> 11, n = tok & 2047;
#pragma unroll
      for (int j = 0; j < 4; j++) {
        const int col0 = n0 + wc + j * 16 + quad * 4;
        const int h = (col0 >> 6) & 15, d = col0 & 63;
        ushort4 o4;
        o4.x = f2bf(acc[i][j][0] * sc); o4.y = f2bf(acc[i][j][1] * sc);
        o4.z = f2bf(acc[i][j][2] * sc); o4.w = f2bf(acc[i][j][3] * sc);
        *(ushort4*)&base[((size_t)(b * 16 + h) * SEQ + n) * 64 + d] = o4;
      }
    }
  } else {
    for (int kt = 0; kt < K; kt += 32) {
      __syncthreads();
#pragma unroll
      for (int i = 0; i < 2; i++) {
        gload_lds16((const void*)(Ag + (size_t)(i * 64) * K + kt), (void*)&Al[i * 2048 + wave * 512]);
        gload_lds16((const void*)(Wg + (size_t)(i * 64) * K + kt), (void*)&Wl[i * 2048 + wave * 512]);
      }
      __syncthreads();
      bf16x8 af[4], wf[4];
#pragma unroll
      for (int i = 0; i < 4; i++) {
        af[i] = *(const bf16x8*)&Al[(wr + i * 16 + l16) * 32 + quad * 8];
        wf[i] = *(const bf16x8*)&Wl[(wc + i * 16 + l16) * 32 + quad * 8];
      }
#pragma unroll
      for (int i = 0; i < 4; i++)
#pragma unroll
        for (int j = 0; j < 4; j++)
          acc[i][j] = __builtin_amdgcn_mfma_f32_16x16x32_bf16(af[i], wf[j], acc[i][j], 0, 0, 0);
    }
    // epilogue (normal frag): 4 consecutive tokens per lane -> V^T fp16 ushort4
#pragma unroll
    for (int i = 0; i < 4; i++) {
      const int row = m0 + wr + i * 16 + quad * 4;
      const int b = row >> 11, n = row & 2047;
#pragma unroll
      for (int j = 0; j < 4; j++) {
        const int col = n0 + wc + j * 16 + l16;
        const int h = (col >> 6) & 15, d = col & 63;
        ushort4 o4;
        o4.x = f2h(acc[i][j][0]); o4.y = f2h(acc[i][j][1]);
        o4.z = f2h(acc[i][j][2]); o4.w = f2h(acc[i][j][3]);
        *(ushort4*)&vtb[((size_t)(b * 16 + h) * 64 + d) * SEQ + n] = o4;
      }
    }
  }
}

// ---- flash attention R7:
// S^T = K*Q^T with PERMUTED key rows: two 16-key tiles T0={8a+b}, T1={8a+4+b}
// per 32-key group, so lane (quad,l16)'s exp'd C-frags concatenate into the
// exact A-frag of mfma_f32_16x16x32_f16 (keys quad*8+0..7). PV at full K=32
// rate, P never touches LDS. Double-buffered K/V, one barrier/iter.
// Grid (bh=64, qtile=8): same-bh blocks land on one XCD (%8) -> L2 reuse.
__global__ __launch_bounds__(256, 2) void attn_kernel(
    const unsigned short* __restrict__ qb,   // [bh][n][d] bf16, pre-scaled by QSCALE
    const unsigned short* __restrict__ kb,   // [bh][n][d] bf16
    const unsigned short* __restrict__ vtb,  // [bh][d][n] fp16
    unsigned short* __restrict__ out) {      // [8192][1024] bf16
  __shared__ unsigned short Kl[2][64 * 64];  // [key][d], chunk c at c^sK(row), sK=(r&3)|((r>>3&1)<<2)
  __shared__ unsigned short Vl[2][64 * 64];  // [d][key] fp16 bits, chunk c at c^(row&7)

  const int tid  = threadIdx.x;
  const int wave = tid >> 6, lane = tid & 63;
  const int quad = lane >> 4, l16 = lane & 15;
  const int bh    = blockIdx.x;           // 0..63  (XCD affinity)
  const int qtile = blockIdx.y;           // 0..7
  const size_t qkbase = (size_t)bh * SEQ * 64;
  const int q0 = qtile * 256 + wave * 64;

  // Q B-frags: Q[n=l16][k=kk*32+quad*8+j]  (kk = d-half here)
  bf16x8 qf[4][2];
#pragma unroll
  for (int mi = 0; mi < 4; mi++)
#pragma unroll
    for (int kk = 0; kk < 2; kk++)
      qf[mi][kk] = *(const bf16x8*)&qb[qkbase + (size_t)(q0 + mi * 16 + l16) * 64 + kk * 32 + quad * 8];

  f32x4 o[4][4];
#pragma unroll
  for (int mi = 0; mi < 4; mi++)
#pragma unroll
    for (int nt = 0; nt < 4; nt++) o[mi][nt] = (f32x4)0.f;
  f32x4 lacc[4];
#pragma unroll
  for (int mi = 0; mi < 4; mi++) lacc[mi] = (f32x4)0.f;

  union { f16x8 v; unsigned int d[4]; } ones8;
#pragma unroll
  for (int j = 0; j < 4; j++) ones8.d[j] = 0x3C003C00u;  // fp16 1.0 x8

  const unsigned short* Kg = kb + qkbase;
  const unsigned short* Vg = vtb + (size_t)bh * 64 * SEQ;
  const int srow = tid >> 3;   // 0..31
  const int schk = tid & 7;
  const int swK = (srow & 3) | (((srow >> 3) & 1) << 2);
  const int swV = srow & 7;

  auto stage = [&](int kt, int buf) {
#pragma unroll
    for (int p = 0; p < 2; p++) {
      const int r = p * 32 + srow;
      gload_lds16((const void*)(Kg + (size_t)(kt + r) * 64 + (schk ^ swK) * 8),
                  (void*)&Kl[buf][p * 2048 + wave * 512]);
      gload_lds16((const void*)(Vg + (size_t)r * SEQ + kt + (schk ^ swV) * 8),
                  (void*)&Vl[buf][p * 2048 + wave * 512]);
    }
  };

  stage(0, 0);

  const int rbase = ((l16 >> 2) << 3) + (l16 & 3);               // 8a + b
  const int sR = (l16 & 3) | (((l16 >> 2) & 1) << 2);            // K read swizzle

  int buf = 0;
  for (int kt = 0; kt < SEQ; kt += 64, buf ^= 1) {
    __syncthreads();  // tile `buf` staged; prev reads of buf^1 done
    if (kt + 64 < SEQ) stage(kt + 64, buf ^ 1);

#pragma unroll
    for (int kk = 0; kk < 2; kk++) {
      // K A-frags, permuted rows: T gives phys keys kk*32 + 8*(l16>>2) + (l16&3) + 4T
      bf16x8 kf[2][2];
#pragma unroll
      for (int T = 0; T < 2; T++) {
        const int R = kk * 32 + rbase + 4 * T;
        kf[T][0] = *(const bf16x8*)&Kl[buf][R * 64 + ((quad ^ sR) << 3)];
        kf[T][1] = *(const bf16x8*)&Kl[buf][R * 64 + (((4 + quad) ^ sR) << 3)];
      }
      // V B-frags: B[n=d=nt*16+l16][k=key=kk*32+quad*8+j]
      f16x8 vf[4];
#pragma unroll
      for (int nt = 0; nt < 4; nt++) {
        const int vr = nt * 16 + l16;
        vf[nt] = *(const f16x8*)&Vl[buf][vr * 64 + (((kk * 4 + quad) ^ (vr & 7)) << 3)];
      }
#pragma unroll
      for (int mi = 0; mi < 4; mi++) {
        // S^T tiles: C[m -> phys key kk*32+8*quad+r(+4T)][n=q=l16]
        f32x4 s0 = (f32x4)0.f, s1 = (f32x4)0.f;
        s0 = MFMA_BF16_K32(kf[0][0], qf[mi][0], s0);
        s0 = MFMA_BF16_K32(kf[0][1], qf[mi][1], s0);
        s1 = MFMA_BF16_K32(kf[1][0], qf[mi][0], s1);
        s1 = MFMA_BF16_K32(kf[1][1], qf[mi][1], s1);
        // P A-frag (16x16x32 f16): lane holds keys kk*32+quad*8+0..7 for q=l16
        union { f16x8 v; unsigned int d[4]; } pu;
        pu.d[0] = pkrtz_bits(EXP2F(s0[0]), EXP2F(s0[1]));
        pu.d[1] = pkrtz_bits(EXP2F(s0[2]), EXP2F(s0[3]));
        pu.d[2] = pkrtz_bits(EXP2F(s1[0]), EXP2F(s1[1]));
        pu.d[3] = pkrtz_bits(EXP2F(s1[2]), EXP2F(s1[3]));
        lacc[mi] = MFMA_F16_K32(pu.v, ones8.v, lacc[mi]);
#pragma unroll
        for (int nt = 0; nt < 4; nt++)
          o[mi][nt] = MFMA_F16_K32(pu.v, vf[nt], o[mi][nt]);
      }
    }
  }

  const int h = bh & 15, b = bh >> 4;
#pragma unroll
  for (int mi = 0; mi < 4; mi++) {
    float inv[4];
#pragma unroll
    for (int r = 0; r < 4; r++) inv[r] = 1.f / lacc[mi][r];
#pragma unroll
    for (int nt = 0; nt < 4; nt++)
#pragma unroll
      for (int r = 0; r < 4; r++)
        out[((size_t)(b * SEQ + q0 + mi * 16 + quad * 4 + r)) * DIM + h * 64 + nt * 16 + l16] =
            f2bf(o[mi][nt][r] * inv[r]);
  }
}

// ---- proj GEMM: out[8192,1024] fp32 = Ao bf16 @ Wproj^T + bias ----
__global__ __launch_bounds__(256) void gemm_proj(
    const unsigned short* __restrict__ A,
    const unsigned short* __restrict__ W,
    float* __restrict__ out,
    const float* __restrict__ bias) {
  const int N = DIM, K = DIM;
  __shared__ unsigned short Al[128 * 32];
  __shared__ unsigned short Wl[128 * 32];
  const int tid  = threadIdx.x;
  const int wave = tid >> 6, lane = tid & 63;
  const int quad = lane >> 4, l16 = lane & 15;
  const int m0 = blockIdx.y * 128, n0 = blockIdx.x * 128;
  const int wr = (wave >> 1) * 64, wc = (wave & 1) * 64;

  f32x4 acc[4][4];
#pragma unroll
  for (int i = 0; i < 4; i++)
#pragma unroll
    for (int j = 0; j < 4; j++) acc[i][j] = (f32x4)0.f;

  const int arow = wave * 16 + (lane >> 2);
  const int acol = (lane & 3) * 8;
  const unsigned short* Ag = A + (size_t)(m0 + arow) * K + acol;
  const unsigned short* Wg = W + (size_t)(n0 + arow) * K + acol;

  for (int kt = 0; kt < K; kt += 32) {
    __syncthreads();
#pragma unroll
    for (int i = 0; i < 2; i++) {
      gload_lds16((const void*)(Ag + (size_t)(i * 64) * K + kt), (void*)&Al[i * 2048 + wave * 512]);
      gload_lds16((const void*)(Wg + (size_t)(i * 64) * K + kt), (void*)&Wl[i * 2048 + wave * 512]);
    }
    __syncthreads();

    bf16x8 af[4], wf[4];
#pragma unroll
    for (int i = 0; i < 4; i++) {
      af[i] = *(const bf16x8*)&Al[(wr + i * 16 + l16) * 32 + quad * 8];
      wf[i] = *(const bf16x8*)&Wl[(wc + i * 16 + l16) * 32 + quad * 8];
    }
#pragma unroll
    for (int i = 0; i < 4; i++)
#pragma unroll
      for (int j = 0; j < 4; j++)
        acc[i][j] = __builtin_amdgcn_mfma_f32_16x16x32_bf16(af[i], wf[j], acc[i][j], 0, 0, 0);
  }

#pragma unroll
  for (int i = 0; i < 4; i++) {
    const int row = m0 + wr + i * 16 + quad * 4;
#pragma unroll
    for (int j = 0; j < 4; j++) {
      const int col = n0 + wc + j * 16 + l16;
      const float bv = bias[col];
#pragma unroll
      for (int r = 0; r < 4; r++)
        out[(size_t)(row + r) * N + col] = acc[i][j][r] + bv;
    }
  }
}

extern "C" void kernel_launch(void* const* d_in, const int* in_sizes, int n_in,
                              void* d_out, int out_size, void* d_ws, size_t ws_size,
                              hipStream_t stream) {
  const float* x      = (const float*)d_in[0];
  const float* w_qkv  = (const float*)d_in[1];
  const float* w_proj = (const float*)d_in[2];
  const float* b_proj = (const float*)d_in[3];
  float* outp = (float*)d_out;

  char* ws = (char*)d_ws;
  unsigned short* xb     = (unsigned short*)(ws);                        // 16 MB
  unsigned short* wqkvb  = (unsigned short*)(ws + (16u << 20));          // 6 MB
  unsigned short* wprojb = (unsigned short*)(ws + (22u << 20));          // 2 MB
  unsigned short* qb     = (unsigned short*)(ws + (24u << 20));          // 16 MB
  unsigned short* kb     = (unsigned short*)(ws + (40u << 20));          // 16 MB
  unsigned short* vtb    = (unsigned short*)(ws + (56u << 20));          // 16 MB (fp16)
  unsigned short* aout   = (unsigned short*)(ws + (72u << 20));          // 16 MB

  const int total4 = (ROWS * DIM + 3 * DIM * DIM + DIM * DIM) / 4;  // 3,145,728
  cast_all<<<total4 / 256, 256, 0, stream>>>(x, w_qkv, w_proj, xb, wqkvb, wprojb);

  gemm_qkv<<<dim3(24, 64), 256, 0, stream>>>(xb, wqkvb, qb, kb, vtb);
  attn_kernel<<<dim3(64, 8), 256, 0, stream>>>(qb, kb, vtb, aout);
  gemm_proj<<<dim3(8, 64), 256, 0, stream>>>(aout, wprojb, outp, b_proj);
}